// Round 3
// baseline (160.759 us; speedup 1.0000x reference)
//
#include <hip/hip_runtime.h>

typedef _Float16 f16;
typedef f16  f16x8 __attribute__((ext_vector_type(8)));
typedef f16  f16x4 __attribute__((ext_vector_type(4)));
typedef f16  f16x2 __attribute__((ext_vector_type(2)));
typedef float f32x4 __attribute__((ext_vector_type(4)));

#define W 512
#define H 512
#define KS 11
#define NW 4                // waves per block
#define NBLK 3072           // 12288 wave-tiles (16x * 64y px) / 4
#define NLINES 256          // spread accumulator lines (64 B apart)
#define C1_SSIM 0.0001f
#define C2_SSIM 0.0009f
#define NTOTAL 12582912.0f

// Normalized separable Gaussian (ksize=11, sigma=1.5), f32 master copy.
__device__ __constant__ const float GW[KS] = {
    1.02838e-3f, 7.59876e-3f, 3.600076e-2f, 1.0936069e-1f, 2.1300554e-1f,
    2.6601172e-1f,
    2.1300554e-1f, 1.0936069e-1f, 3.600076e-2f, 7.59876e-3f, 1.02838e-3f
};

__device__ inline float ssim_px(float ux, float uy, float uxx, float uyy, float uxy) {
    const float uxuy = ux * uy;
    const float a = 2.f * uxuy + C1_SSIM;
    const float b = 2.f * (uxy - uxuy) + C2_SSIM;
    const float c = ux * ux + uy * uy + C1_SSIM;
    const float d = (uxx - ux * ux) + (uyy - uy * uy) + C2_SSIM;
    return (a * b) * __builtin_amdgcn_rcpf(c * d);
}

struct __attribute__((aligned(4))) F4 { float x, y, z, w; };

// edge flag is wave-uniform (function of tx/ty/g only): interior waves get a
// straight-line 2x dwordx4 path; edge waves take the per-lane checked path.
__device__ __forceinline__ void load8f(const float* __restrict__ base, int ry,
                                       int xs, float v[8], bool edge) {
    if (!edge) {
        const float* r = base + ((size_t)ry << 9);
        const F4 a = *(const F4*)(r + xs);
        const F4 b = *(const F4*)(r + xs + 4);
        v[0] = a.x; v[1] = a.y; v[2] = a.z; v[3] = a.w;
        v[4] = b.x; v[5] = b.y; v[6] = b.z; v[7] = b.w;
    } else if ((unsigned)ry < (unsigned)H) {
        const float* r = base + ((size_t)ry << 9);
        #pragma unroll
        for (int j = 0; j < 8; ++j) {
            const int x = xs + j;
            v[j] = ((unsigned)x < (unsigned)W) ? r[x] : 0.f;
        }
    } else {
        #pragma unroll
        for (int j = 0; j < 8; ++j) v[j] = 0.f;
    }
}

__device__ __forceinline__ f16x8 pack8(const float v[8]) {
    f16x8 r;
    #pragma unroll
    for (int p = 0; p < 4; ++p) {
        const f16x2 h = __builtin_bit_cast(
            f16x2, __builtin_amdgcn_cvt_pkrtz(v[2 * p], v[2 * p + 1]));
        r[2 * p]     = h[0];
        r[2 * p + 1] = h[1];
    }
    return r;
}

// One wave = 16(x) x 64(y) outputs, 5 row groups (16 image rows each).
// KEY CHANGE vs previous version: rolling 3-slot register staging with a
// STRUCTURAL prefetch distance of 2 groups.  Each iteration issues the
// loads for group g+2, then a sched_barrier(0) fence pins them above the
// compute of group g -- the compiler cannot sink them (which is what
// silently killed the previous upfront-load attempt: VGPR stayed 64, i.e.
// loads were rescheduled to their uses).  Steady state: entering pack(g),
// the 8 dwordx4 of groups g+1,g+2 are in flight (counted vmcnt, never a
// full drain), and ~2 groups of compute (~1000 cy) covers L2/HBM latency.
// Compute pipeline unchanged: hconv D=mfma_16x16x32(img, af) (lane=xout,
// rows y at quad*4+reg), packed lane-locally into the vconv B operand of
// two chained K=16 MFMAs (B[k][n] layout k=4*(lane>>4)+j matches the hconv
// D row layout exactly -- zero cross-lane movement).
__global__ __launch_bounds__(256, 3)
void ssim_main(const float* __restrict__ simg, const float* __restrict__ timg,
               float* __restrict__ accum) {
    __shared__ float red[NW];

    const int tid  = threadIdx.x;
    const int w    = tid >> 6;
    const int lane = tid & 63;
    const int n    = lane & 15;
    const int q    = lane >> 4;

    const int L  = blockIdx.x * NW + w;   // wave-tile id (16x x 64y)
    const int z  = L >> 8;                // slice: 32 x-tiles * 8 y-tiles
    const int r  = L & 255;
    const int ty = r >> 5;
    const int tx = r & 31;

    const float* sp = simg + ((size_t)z << 18);
    const float* tp = timg + ((size_t)z << 18);
    const int x0 = tx << 4;
    const int y0 = (ty << 6) - 5;         // stored row 0 (80 rows: 5 groups)
    const int xs = x0 - 5 + (q << 3);     // this lane's 8-col x window

    const bool xedge = (tx == 0) | (tx == 31);

    // ---- Prologue: issue loads for groups 0 and 1, pin them high ----
    float va[3][8], vb[3][8];
    #pragma unroll
    for (int g = 0; g < 2; ++g) {
        const bool e = xedge | (ty == 0 && g == 0);
        load8f(sp, y0 + (g << 4) + n, xs, va[g], e);
        load8f(tp, y0 + (g << 4) + n, xs, vb[g], e);
    }
    __builtin_amdgcn_sched_barrier(0);

    // Fragment setup runs under the in-flight loads.
    // hconv banded-weight fragment (B operand, K=32): B[k][j]=G[k-j].
    f16x8 af;
    #pragma unroll
    for (int j = 0; j < 8; ++j) {
        const int k = (q << 3) + j;
        const int d = k - n;
        af[j] = (d >= 0 && d < KS) ? (f16)GW[d] : (f16)0.f;
    }
    // vconv banded-weight fragments (A operands, K=16): lane holds
    // A[m=n][k=4q+j].  a1: taps in group t (d=k-n); a2: spill into group
    // t+1 (d=k+16-n).
    f16x4 a1v, a2v;
    #pragma unroll
    for (int j = 0; j < 4; ++j) {
        const int k  = (q << 2) + j;
        const int d1 = k - n;
        const int d2 = k + 16 - n;
        a1v[j] = (d1 >= 0 && d1 < KS) ? (f16)GW[d1] : (f16)0.f;
        a2v[j] = (d2 >= 0 && d2 < KS) ? (f16)GW[d2] : (f16)0.f;
    }

    union H4 { f16x4 v4; f16x2 v2[2]; };

    f16x4 ph[2][5];                        // packed hconv rows, parity dbuf
    float sum = 0.f;

    #pragma unroll
    for (int g = 0; g < 5; ++g) {
        // Issue loads for group g+2 into the free slot, pin above compute.
        if (g + 2 < 5) {
            const int gn = g + 2;
            const bool e = xedge | (ty == 7 && gn == 4);
            load8f(sp, y0 + (gn << 4) + n, xs, va[gn % 3], e);
            load8f(tp, y0 + (gn << 4) + n, xs, vb[gn % 3], e);
        }
        __builtin_amdgcn_sched_barrier(0);

        const int s = g % 3;
        const f16x8 sf = pack8(va[s]);
        const f16x8 tf = pack8(vb[s]);
        const int pb = g & 1;
        #pragma unroll
        for (int c = 0; c < 5; ++c) {
            f16x8 ch;
            if      (c == 0) ch = sf;
            else if (c == 1) ch = tf;
            else if (c == 2) ch = sf * sf;
            else if (c == 3) ch = tf * tf;
            else             ch = sf * tf;
            const f32x4 zero = {0.f, 0.f, 0.f, 0.f};
            const f32x4 d = __builtin_amdgcn_mfma_f32_16x16x32_f16(ch, af, zero, 0, 0, 0);
            H4 u;
            u.v2[0] = __builtin_bit_cast(f16x2, __builtin_amdgcn_cvt_pkrtz(d[0], d[1]));
            u.v2[1] = __builtin_bit_cast(f16x2, __builtin_amdgcn_cvt_pkrtz(d[2], d[3]));
            ph[pb][c] = u.v4;              // lane-local: rows 4q..4q+3 at xout=n
        }
        if (g >= 1) {
            const int pa = pb ^ 1;        // group t = g-1
            f32x4 acc[5];
            #pragma unroll
            for (int c = 0; c < 5; ++c) {
                const f32x4 zero = {0.f, 0.f, 0.f, 0.f};
                f32x4 a = __builtin_amdgcn_mfma_f32_16x16x16f16(a2v, ph[pb][c], zero, 0, 0, 0);
                a = __builtin_amdgcn_mfma_f32_16x16x16f16(a1v, ph[pa][c], a, 0, 0, 0);
                acc[c] = a;
            }
            #pragma unroll
            for (int rg = 0; rg < 4; ++rg)
                sum += ssim_px(acc[0][rg], acc[1][rg], acc[2][rg],
                               acc[3][rg], acc[4][rg]);
        }
    }

    // ---- Wave reduce, block reduce, one spread atomic per block ----
    #pragma unroll
    for (int off = 32; off > 0; off >>= 1)
        sum += __shfl_down(sum, off, 64);
    if (lane == 0) red[w] = sum;
    __syncthreads();
    if (tid == 0) {
        atomicAdd(&accum[(blockIdx.x & (NLINES - 1)) << 4],
                  red[0] + red[1] + red[2] + red[3]);
    }
}

__global__ void ssim_final(const float* __restrict__ accum, float* __restrict__ out) {
    const int lane = threadIdx.x;
    float s = 0.f;
    #pragma unroll
    for (int i = 0; i < NLINES / 64; ++i)
        s += accum[((i << 6) + lane) << 4];
    #pragma unroll
    for (int off = 32; off > 0; off >>= 1)
        s += __shfl_down(s, off, 64);
    if (lane == 0) out[0] = 1.f - s * (1.f / NTOTAL);
}

extern "C" void kernel_launch(void* const* d_in, const int* in_sizes, int n_in,
                              void* d_out, int out_size, void* d_ws, size_t ws_size,
                              hipStream_t stream) {
    const float* s = (const float*)d_in[0];
    const float* t = (const float*)d_in[1];
    float* out   = (float*)d_out;
    float* accum = (float*)d_ws;   // NLINES * 16 floats = 16 KB scratch

    hipMemsetAsync(accum, 0, NLINES * 16 * sizeof(float), stream);
    ssim_main<<<dim3(NBLK), 256, 0, stream>>>(s, t, accum);
    ssim_final<<<1, 64, 0, stream>>>(accum, out);
}

// Round 4
// 139.105 us; speedup vs baseline: 1.1557x; 1.1557x over previous
//
#include <hip/hip_runtime.h>

typedef _Float16 f16;
typedef f16  f16x8 __attribute__((ext_vector_type(8)));
typedef f16  f16x4 __attribute__((ext_vector_type(4)));
typedef f16  f16x2 __attribute__((ext_vector_type(2)));
typedef float f32x4 __attribute__((ext_vector_type(4)));

#define W 512
#define H 512
#define KS 11
#define NW 4                // waves per block
#define NBLK 3072           // 48 slices * 8 ty * 8 tx (64x64 tile per block)
#define NLINES 256          // spread accumulator lines (64 B apart)
#define C1_SSIM 0.0001f
#define C2_SSIM 0.0009f
#define NTOTAL 12582912.0f

// LDS tile per image: 80 rows x 80 f16 cols, stride 80 f16 (160 B).
// 160 B stride => fragment ds_read_b128 word addr = 40*lr + 8w + 4q + c:
// exactly 8 accesses per bank (the 8-cycle floor, zero conflict overhead).
#define LROWS 80
#define LSTRIDE 80          // f16 units

// Normalized separable Gaussian (ksize=11, sigma=1.5), f32 master copy.
__device__ __constant__ const float GW[KS] = {
    1.02838e-3f, 7.59876e-3f, 3.600076e-2f, 1.0936069e-1f, 2.1300554e-1f,
    2.6601172e-1f,
    2.1300554e-1f, 1.0936069e-1f, 3.600076e-2f, 7.59876e-3f, 1.02838e-3f
};

__device__ inline float ssim_px(float ux, float uy, float uxx, float uyy, float uxy) {
    const float uxuy = ux * uy;
    const float a = 2.f * uxuy + C1_SSIM;
    const float b = 2.f * (uxy - uxuy) + C2_SSIM;
    const float c = ux * ux + uy * uy + C1_SSIM;
    const float d = (uxx - ux * ux) + (uyy - uy * uy) + C2_SSIM;
    return (a * b) * __builtin_amdgcn_rcpf(c * d);
}

struct __attribute__((aligned(16))) F4 { float x, y, z, w; };

__device__ __forceinline__ f16x8 pack8(const float v[8]) {
    f16x8 r;
    #pragma unroll
    for (int p = 0; p < 4; ++p) {
        const f16x2 h = __builtin_bit_cast(
            f16x2, __builtin_amdgcn_cvt_pkrtz(v[2 * p], v[2 * p + 1]));
        r[2 * p]     = h[0];
        r[2 * p + 1] = h[1];
    }
    return r;
}

// Block = 4 waves = one 64x64 output tile (wave w owns the 16-col slice
// 16w..16w+15, all 64 rows).  PHASE 1: all 256 threads stage the 80x80
// input window of both images into LDS as f16 (fully aligned 8-float f32
// loads from col x0-8; x-OOB segments are exactly 8-aligned so each task is
// all-in or all-out -> no ragged lanes).  PHASE 2: compute entirely from
// LDS.  The -5 window offset is absorbed into the hconv band (d = k-n-3),
// keeping BOTH the global loads and the ds_read_b128 fragments 16B-aligned.
// hconv: D=mfma_16x16x32(img_frag, af) (lane=xout col x0+16w+n, rows
// 4q+reg); vconv: two chained K=16 MFMAs on lane-local packed hconv rows
// (identical fragment algebra to the previous absmax-0.0 kernel).
// Latency hiding is by OCCUPANCY: 25.6 KB LDS -> 6 blocks/CU = 24 waves/CU;
// staging loads of one block overlap compute of the other resident blocks.
__global__ __launch_bounds__(256, 6)
void ssim_main(const float* __restrict__ simg, const float* __restrict__ timg,
               float* __restrict__ accum) {
    __shared__ __align__(16) f16 lds[2][LROWS * LSTRIDE];
    __shared__ float red[NW];

    const int tid  = threadIdx.x;
    const int w    = tid >> 6;
    const int lane = tid & 63;
    const int n    = lane & 15;
    const int q    = lane >> 4;

    const int bid = blockIdx.x;
    const int z   = bid >> 6;             // 48 slices (16 batch * 3 ch)
    const int rr  = bid & 63;
    const int ty  = rr >> 3;
    const int tx  = rr & 7;

    const float* sp = simg + ((size_t)z << 18);
    const float* tp = timg + ((size_t)z << 18);
    const int x0    = tx << 6;
    const int ybase = (ty << 6) - 5;      // stored row 0 (80 rows)
    const int xbase = x0 - 8;             // stored col 0 (80 cols, aligned)

    // ---- PHASE 1: cooperative staging (1600 tasks of 8 floats each) ----
    // task t: img = t/800, u = t%800, lr = u/10, seg = u%10.
    #pragma unroll
    for (int it = 0; it < 7; ++it) {
        const int t = it * 256 + tid;
        if (it < 6 || t < 1600) {
            const int img = (t >= 800) ? 1 : 0;
            const int u   = img ? (t - 800) : t;
            const int lr  = (u * 205) >> 11;       // u/10 for u<800
            const int sg  = u - lr * 10;
            const int ry  = ybase + lr;
            const int cx  = xbase + (sg << 3);
            const float* src = img ? tp : sp;
            float v[8];
            const bool ok = ((unsigned)ry < (unsigned)H) &
                            ((unsigned)cx <= (unsigned)(W - 8));
            if (ok) {
                const float* rp = src + ((size_t)ry << 9) + cx;
                const F4 a = *(const F4*)rp;
                const F4 b = *(const F4*)(rp + 4);
                v[0] = a.x; v[1] = a.y; v[2] = a.z; v[3] = a.w;
                v[4] = b.x; v[5] = b.y; v[6] = b.z; v[7] = b.w;
            } else {
                #pragma unroll
                for (int j = 0; j < 8; ++j) v[j] = 0.f;
            }
            *(f16x8*)&lds[img][lr * LSTRIDE + (sg << 3)] = pack8(v);
        }
    }

    // Fragment setup (overlaps staging latency).
    // hconv band (B operand, K=32), shifted by the 3-col aligned margin:
    // A[m][k] = img[row][x0+16w-8+k]  =>  B[k][n] = G[k-n-3].
    f16x8 af;
    #pragma unroll
    for (int j = 0; j < 8; ++j) {
        const int k = (q << 3) + j;
        const int d = k - n - 3;
        af[j] = (d >= 0 && d < KS) ? (f16)GW[d] : (f16)0.f;
    }
    // vconv bands (A operands, K=16): a1 taps in group t (d=k-n), a2 spill
    // into group t+1 (d=k+16-n).  Unchanged from verified version.
    f16x4 a1v, a2v;
    #pragma unroll
    for (int j = 0; j < 4; ++j) {
        const int k  = (q << 2) + j;
        const int d1 = k - n;
        const int d2 = k + 16 - n;
        a1v[j] = (d1 >= 0 && d1 < KS) ? (f16)GW[d1] : (f16)0.f;
        a2v[j] = (d2 >= 0 && d2 < KS) ? (f16)GW[d2] : (f16)0.f;
    }

    __syncthreads();

    // ---- PHASE 2: compute from LDS ----
    union H4 { f16x4 v4; f16x2 v2[2]; };
    const int coff = (w << 4) + (q << 3);   // f16 col offset: 16w + 8q
    const f16* lss = &lds[0][coff];
    const f16* lts = &lds[1][coff];

    f16x4 ph[2][5];                        // packed hconv rows, parity dbuf
    float sum = 0.f;

    #pragma unroll
    for (int g = 0; g < 5; ++g) {
        const int rowoff = ((g << 4) + n) * LSTRIDE;
        const f16x8 sf = *(const f16x8*)(lss + rowoff);
        const f16x8 tf = *(const f16x8*)(lts + rowoff);
        const int pb = g & 1;
        #pragma unroll
        for (int c = 0; c < 5; ++c) {
            f16x8 ch;
            if      (c == 0) ch = sf;
            else if (c == 1) ch = tf;
            else if (c == 2) ch = sf * sf;
            else if (c == 3) ch = tf * tf;
            else             ch = sf * tf;
            const f32x4 zero = {0.f, 0.f, 0.f, 0.f};
            const f32x4 d = __builtin_amdgcn_mfma_f32_16x16x32_f16(ch, af, zero, 0, 0, 0);
            H4 u;
            u.v2[0] = __builtin_bit_cast(f16x2, __builtin_amdgcn_cvt_pkrtz(d[0], d[1]));
            u.v2[1] = __builtin_bit_cast(f16x2, __builtin_amdgcn_cvt_pkrtz(d[2], d[3]));
            ph[pb][c] = u.v4;              // lane-local: rows 4q..4q+3 at col 16w+n
        }
        if (g >= 1) {
            const int pa = pb ^ 1;        // group t = g-1
            f32x4 acc[5];
            #pragma unroll
            for (int c = 0; c < 5; ++c) {
                const f32x4 zero = {0.f, 0.f, 0.f, 0.f};
                f32x4 a = __builtin_amdgcn_mfma_f32_16x16x16f16(a2v, ph[pb][c], zero, 0, 0, 0);
                a = __builtin_amdgcn_mfma_f32_16x16x16f16(a1v, ph[pa][c], a, 0, 0, 0);
                acc[c] = a;
            }
            #pragma unroll
            for (int rg = 0; rg < 4; ++rg)
                sum += ssim_px(acc[0][rg], acc[1][rg], acc[2][rg],
                               acc[3][rg], acc[4][rg]);
        }
    }

    // ---- Wave reduce, block reduce, one spread atomic per block ----
    #pragma unroll
    for (int off = 32; off > 0; off >>= 1)
        sum += __shfl_down(sum, off, 64);
    if (lane == 0) red[w] = sum;
    __syncthreads();
    if (tid == 0) {
        atomicAdd(&accum[(blockIdx.x & (NLINES - 1)) << 4],
                  red[0] + red[1] + red[2] + red[3]);
    }
}

__global__ void ssim_final(const float* __restrict__ accum, float* __restrict__ out) {
    const int lane = threadIdx.x;
    float s = 0.f;
    #pragma unroll
    for (int i = 0; i < NLINES / 64; ++i)
        s += accum[((i << 6) + lane) << 4];
    #pragma unroll
    for (int off = 32; off > 0; off >>= 1)
        s += __shfl_down(s, off, 64);
    if (lane == 0) out[0] = 1.f - s * (1.f / NTOTAL);
}

extern "C" void kernel_launch(void* const* d_in, const int* in_sizes, int n_in,
                              void* d_out, int out_size, void* d_ws, size_t ws_size,
                              hipStream_t stream) {
    const float* s = (const float*)d_in[0];
    const float* t = (const float*)d_in[1];
    float* out   = (float*)d_out;
    float* accum = (float*)d_ws;   // NLINES * 16 floats = 16 KB scratch

    hipMemsetAsync(accum, 0, NLINES * 16 * sizeof(float), stream);
    ssim_main<<<dim3(NBLK), 256, 0, stream>>>(s, t, accum);
    ssim_final<<<1, 64, 0, stream>>>(accum, out);
}

// Round 5
// 138.472 us; speedup vs baseline: 1.1610x; 1.0046x over previous
//
#include <hip/hip_runtime.h>
#include <stdint.h>

typedef _Float16 f16;
typedef f16  f16x8 __attribute__((ext_vector_type(8)));
typedef f16  f16x4 __attribute__((ext_vector_type(4)));
typedef f16  f16x2 __attribute__((ext_vector_type(2)));
typedef float f32x4 __attribute__((ext_vector_type(4)));

#define W 512
#define H 512
#define KS 11
#define NW 4                // waves per block
#define NBLK 3072           // 48 slices * 8 ty * 8 tx (64x64 tile per block)
#define NLINES 256          // spread accumulator lines (64 B apart)
#define C1_SSIM 0.0001f
#define C2_SSIM 0.0009f
#define NTOTAL 12582912.0f

// LDS tile per image: 80 rows x 80 f32 (320 B row stride).  2 images =
// 51.2 KB -> 3 blocks/CU.  Staged by global_load_lds async DMA in 50
// 1-KB wave-chunks; chunk c covers LDS bytes [c*1024, c*1024+1024).
#define LROWS 80
#define LCOLS 80            // f32 units
#define NCHUNK 50           // 2 * 80*80*4 / 1024

// Normalized separable Gaussian (ksize=11, sigma=1.5), f32 master copy.
__device__ __constant__ const float GW[KS] = {
    1.02838e-3f, 7.59876e-3f, 3.600076e-2f, 1.0936069e-1f, 2.1300554e-1f,
    2.6601172e-1f,
    2.1300554e-1f, 1.0936069e-1f, 3.600076e-2f, 7.59876e-3f, 1.02838e-3f
};

__device__ inline float ssim_px(float ux, float uy, float uxx, float uyy, float uxy) {
    const float uxuy = ux * uy;
    const float a = 2.f * uxuy + C1_SSIM;
    const float b = 2.f * (uxy - uxuy) + C2_SSIM;
    const float c = ux * ux + uy * uy + C1_SSIM;
    const float d = (uxx - ux * ux) + (uyy - uy * uy) + C2_SSIM;
    return (a * b) * __builtin_amdgcn_rcpf(c * d);
}

__device__ __forceinline__ f16x8 pack84(f32x4 a, f32x4 b) {
    f16x8 r;
    f16x2 h;
    h = __builtin_bit_cast(f16x2, __builtin_amdgcn_cvt_pkrtz(a[0], a[1]));
    r[0] = h[0]; r[1] = h[1];
    h = __builtin_bit_cast(f16x2, __builtin_amdgcn_cvt_pkrtz(a[2], a[3]));
    r[2] = h[0]; r[3] = h[1];
    h = __builtin_bit_cast(f16x2, __builtin_amdgcn_cvt_pkrtz(b[0], b[1]));
    r[4] = h[0]; r[5] = h[1];
    h = __builtin_bit_cast(f16x2, __builtin_amdgcn_cvt_pkrtz(b[2], b[3]));
    r[6] = h[0]; r[7] = h[1];
    return r;
}

// Block = 4 waves = one 64x64 output tile.  PHASE 1: async global->LDS DMA
// (global_load_lds dwordx4): 50 x 1 KB chunks, wave w issues chunks w,w+4,
// ... back-to-back with NO register round-trip -- the compiler cannot
// serialize this (the failure mode of the reg-staged versions: loads were
// always sunk to their uses).  Staging cost ~= issue + ONE memory latency,
// drained by the vmcnt(0) implicit in __syncthreads.  Border zero-padding:
// OOB lanes point their per-lane GLOBAL source at a zeroed 16-B workspace
// line (LDS dest must stay linear; 8-col alignment makes every 16-B chunk
// all-in or all-out).  PHASE 2: fragments read two f32x4 from LDS (320-B
// stride => 2-way bank aliasing, free) and cvt_pkrtz-pack in place; hconv
// D=mfma_16x16x32(img, af) with the -8-col window absorbed in the band
// (d=k-n-3); vconv = two chained K=16 MFMAs on lane-local packed rows.
// Fragment algebra identical to the verified absmax-0.0 R4 kernel.
__global__ __launch_bounds__(256, 3)
void ssim_main(const float* __restrict__ simg, const float* __restrict__ timg,
               float* __restrict__ accum, const float* __restrict__ zbuf) {
    __shared__ __align__(16) float lds[2][LROWS * LCOLS];
    __shared__ float red[NW];

    const int tid  = threadIdx.x;
    const int w    = tid >> 6;
    const int lane = tid & 63;
    const int n    = lane & 15;
    const int q    = lane >> 4;

    const int bid = blockIdx.x;
    const int z   = bid >> 6;             // 48 slices (16 batch * 3 ch)
    const int rr  = bid & 63;
    const int ty  = rr >> 3;
    const int tx  = rr & 7;

    const float* sp = simg + ((size_t)z << 18);
    const float* tp = timg + ((size_t)z << 18);
    const int x0    = tx << 6;
    const int ybase = (ty << 6) - 5;      // stored row 0 (80 rows)
    const int xbase = x0 - 8;             // stored col 0 (80 cols, aligned)

    // ---- PHASE 1: async DMA staging ----
    #pragma unroll
    for (int k = 0; k < 13; ++k) {
        const int c = (k << 2) + w;       // wave-uniform chunk id
        if (c < NCHUNK) {
            const int img  = (c >= 25) ? 1 : 0;
            const int cc   = img ? (c - 25) : c;
            const int off  = (cc << 10) + (lane << 4);   // byte in image tile
            const int t    = off >> 6;                    // off/64 < 400
            const int row  = (t * 205) >> 10;             // off/320
            const int colb = off - row * 320;
            const int ry   = ybase + row;
            const int gcol = xbase + (colb >> 2);
            const float* src = img ? tp : sp;
            const bool ok = ((unsigned)ry < (unsigned)H) &
                            ((unsigned)gcol <= (unsigned)(W - 4));
            const float* ga = ok ? (src + ((size_t)ry << 9) + gcol) : zbuf;
            void* ldst = (char*)(&lds[0][0]) + (c << 10); // wave-uniform dest
            __builtin_amdgcn_global_load_lds(
                (const uint32_t __attribute__((address_space(1)))*)ga,
                (uint32_t __attribute__((address_space(3)))*)ldst,
                16, 0, 0);
        }
    }

    // Fragment setup overlaps the in-flight DMA.
    // hconv band (B operand, K=32): A cols start at xbase+16w => d = k-n-3.
    f16x8 af;
    #pragma unroll
    for (int j = 0; j < 8; ++j) {
        const int k = (q << 3) + j;
        const int d = k - n - 3;
        af[j] = (d >= 0 && d < KS) ? (f16)GW[d] : (f16)0.f;
    }
    // vconv bands (A operands, K=16): a1 taps in group t (d=k-n), a2 spill
    // into group t+1 (d=k+16-n).
    f16x4 a1v, a2v;
    #pragma unroll
    for (int j = 0; j < 4; ++j) {
        const int k  = (q << 2) + j;
        const int d1 = k - n;
        const int d2 = k + 16 - n;
        a1v[j] = (d1 >= 0 && d1 < KS) ? (f16)GW[d1] : (f16)0.f;
        a2v[j] = (d2 >= 0 && d2 < KS) ? (f16)GW[d2] : (f16)0.f;
    }

    __syncthreads();   // drains vmcnt(0): all DMA landed

    // ---- PHASE 2: compute from LDS ----
    union H4 { f16x4 v4; f16x2 v2[2]; };
    const int coff = (w << 4) + (q << 3);   // f32 col offset: 16w + 8q
    const float* ls = &lds[0][coff];
    const float* lt = &lds[1][coff];

    f16x4 ph[2][5];                        // packed hconv rows, parity dbuf
    float sum = 0.f;

    #pragma unroll
    for (int g = 0; g < 5; ++g) {
        const int ro = ((g << 4) + n) * LCOLS;
        const f32x4 s0 = *(const f32x4*)(ls + ro);
        const f32x4 s1 = *(const f32x4*)(ls + ro + 4);
        const f32x4 t0 = *(const f32x4*)(lt + ro);
        const f32x4 t1 = *(const f32x4*)(lt + ro + 4);
        const f16x8 sf = pack84(s0, s1);
        const f16x8 tf = pack84(t0, t1);
        const int pb = g & 1;
        #pragma unroll
        for (int c = 0; c < 5; ++c) {
            f16x8 ch;
            if      (c == 0) ch = sf;
            else if (c == 1) ch = tf;
            else if (c == 2) ch = sf * sf;
            else if (c == 3) ch = tf * tf;
            else             ch = sf * tf;
            const f32x4 zero = {0.f, 0.f, 0.f, 0.f};
            const f32x4 d = __builtin_amdgcn_mfma_f32_16x16x32_f16(ch, af, zero, 0, 0, 0);
            H4 u;
            u.v2[0] = __builtin_bit_cast(f16x2, __builtin_amdgcn_cvt_pkrtz(d[0], d[1]));
            u.v2[1] = __builtin_bit_cast(f16x2, __builtin_amdgcn_cvt_pkrtz(d[2], d[3]));
            ph[pb][c] = u.v4;              // lane-local: rows 4q..4q+3 at col 16w+n
        }
        if (g >= 1) {
            const int pa = pb ^ 1;        // group t = g-1
            f32x4 acc[5];
            #pragma unroll
            for (int c = 0; c < 5; ++c) {
                const f32x4 zero = {0.f, 0.f, 0.f, 0.f};
                f32x4 a = __builtin_amdgcn_mfma_f32_16x16x16f16(a2v, ph[pb][c], zero, 0, 0, 0);
                a = __builtin_amdgcn_mfma_f32_16x16x16f16(a1v, ph[pa][c], a, 0, 0, 0);
                acc[c] = a;
            }
            #pragma unroll
            for (int rg = 0; rg < 4; ++rg)
                sum += ssim_px(acc[0][rg], acc[1][rg], acc[2][rg],
                               acc[3][rg], acc[4][rg]);
        }
    }

    // ---- Wave reduce, block reduce, one spread atomic per block ----
    #pragma unroll
    for (int off = 32; off > 0; off >>= 1)
        sum += __shfl_down(sum, off, 64);
    if (lane == 0) red[w] = sum;
    __syncthreads();
    if (tid == 0) {
        atomicAdd(&accum[(blockIdx.x & (NLINES - 1)) << 4],
                  red[0] + red[1] + red[2] + red[3]);
    }
}

__global__ void ssim_final(const float* __restrict__ accum, float* __restrict__ out) {
    const int lane = threadIdx.x;
    float s = 0.f;
    #pragma unroll
    for (int i = 0; i < NLINES / 64; ++i)
        s += accum[((i << 6) + lane) << 4];
    #pragma unroll
    for (int off = 32; off > 0; off >>= 1)
        s += __shfl_down(s, off, 64);
    if (lane == 0) out[0] = 1.f - s * (1.f / NTOTAL);
}

extern "C" void kernel_launch(void* const* d_in, const int* in_sizes, int n_in,
                              void* d_out, int out_size, void* d_ws, size_t ws_size,
                              hipStream_t stream) {
    const float* s = (const float*)d_in[0];
    const float* t = (const float*)d_in[1];
    float* out   = (float*)d_out;
    float* accum = (float*)d_ws;                 // NLINES*16 floats = 16 KB
    const float* zbuf = accum + NLINES * 16;     // 16-B+ zeroed line for OOB DMA

    // zero accumulator lines + the OOB zero line in one memset
    hipMemsetAsync(accum, 0, NLINES * 16 * sizeof(float) + 256, stream);
    ssim_main<<<dim3(NBLK), 256, 0, stream>>>(s, t, accum, zbuf);
    ssim_final<<<1, 64, 0, stream>>>(accum, out);
}